// Round 13
// baseline (965.940 us; speedup 1.0000x reference)
//
#include <hip/hip_runtime.h>

#define NN 50000
#define EE 640000
#define RR 8
#define CAP 48        // per-dst edge capacity; deg ~ Binom(640K,1/50K) mean 12.8, P(deg>48)~3e-8
#define CSTRIDE 16    // cursor padded to 1 counter per 64B line (r11: -23MB RMW, -12us)

typedef __bf16 bf16x8 __attribute__((ext_vector_type(8)));
typedef float  f32x4  __attribute__((ext_vector_type(4)));

__device__ __forceinline__ unsigned short f2b(float f) {
  unsigned int u = __float_as_uint(f);
  u += 0x7fffu + ((u >> 16) & 1u);          // round-to-nearest-even
  return (unsigned short)(u >> 16);
}
__device__ __forceinline__ float b2f(unsigned short h) {
  return __uint_as_float(((unsigned int)h) << 16);
}

// ---- prologue: x f32->bf16 | build B1^T | build B2^T | edge-list build.
// Edges must precede the fused layer-1 kernel (it consumes entries during its
// aggregation passes), so they live here, overlapping the conv on other blocks.
// cursor zeroed by hipMemsetAsync before this kernel.
#define CONV_N 1600000            // float4 count for x (50000*128/4)
#define B1_N (1152 * 128)
#define B2_N (640 * 128)
__global__ void k_prologue(const float* __restrict__ x, unsigned short* __restrict__ xb,
                           const float* __restrict__ W1, const float* __restrict__ root1,
                           unsigned short* __restrict__ B1T,
                           const float* __restrict__ W2, const float* __restrict__ root2,
                           unsigned short* __restrict__ B2T,
                           const int* __restrict__ srcI, const int* __restrict__ dstI,
                           const int* __restrict__ typ,
                           int* __restrict__ cursor, unsigned int* __restrict__ entries) {
  int t = blockIdx.x * 256 + threadIdx.x;
  if (t < CONV_N) {
    float4 v = reinterpret_cast<const float4*>(x)[t];
    ushort4 o = make_ushort4(f2b(v.x), f2b(v.y), f2b(v.z), f2b(v.w));
    reinterpret_cast<ushort4*>(xb)[t] = o;
    return;
  }
  t -= CONV_N;
  if (t < B1_N) {   // B1^T [1152][128]: rows j = r*128+o (r<8), then root1
    int j = t >> 7, k = t & 127;
    float v = (j < 1024) ? W1[((j >> 7) << 14) + (k << 7) + (j & 127)]
                         : root1[(k << 7) + (j - 1024)];
    B1T[t] = f2b(v);
    return;
  }
  t -= B1_N;
  if (t < B2_N) {   // B2^T [640][128]: rows j = r*64+o (r<8), root2, zero-pad
    int j = t >> 7, k = t & 127;
    float v = 0.0f;
    if (j < 512)      v = W2[((j >> 6) << 13) + (k << 6) + (j & 63)];
    else if (j < 576) v = root2[(k << 6) + (j - 512)];
    B2T[t] = f2b(v);
    return;
  }
  t -= B2_N;
  if (t < EE) {     // edge-list build: one thread per edge, padded-cursor atomics
    int d = dstI[t], r = typ[t];
    int pos = atomicAdd(&cursor[d * CSTRIDE], 1);
    if (pos < CAP)
      entries[(size_t)d * CAP + pos] = (unsigned int)srcI[t] | ((unsigned int)r << 16);
  }
}

// ---- FUSED RGCN LAYER: aggregate-then-transform. Never materializes y = x@W
// (r11's y1 cost 102MB write + 133MB HBM re-fetch). Per block of 128 dsts:
//   for r in 0..7: build m_r[128dst][128feat] in LDS (v5-agg1-style gather of
//     X rows — X is 12.8MB, L2/LLC-resident — filtered to rel==r, mean-scaled,
//     XOR-swizzled store) -> MFMA acc += m_r @ W_r (B rows r*NOUT..+NOUT-1).
//   root pass: A = X rows d0..d0+127 (contiguous, direct) @ B rows 8*NOUT.
//   + bias, ReLU. CLS=false: write H bf16 [N][128] via shfl-transpose.
//   CLS=true (layer 2): h2 -> LDS f32 [128][68 padded] -> fused classifier
//     (out[d][2] = h2 @ Wc + bc), writes only 400KB.
// Swizzle invariant (verified r1-r11): logical 16B chunk j of row p stored at
// physical chunk j^(p&15); MFMA reads sw = ((kk*4+quad)^l15)*8.
// Audited r13: no OOB (all index maxima checked), no barrier divergence (all
// waves run identical trip counts), LDS alias hs/Ms ordered by the r-loop's
// final barrier, 34816B x 3 blocks/CU = 104KB <= 160KB.
template <int NOUT, bool CLS>
__global__ __launch_bounds__(256, 3) void k_fused(
    const unsigned short* __restrict__ X,   // [N][128] bf16 (xb or h1)
    const unsigned short* __restrict__ BT,  // B^T: rows r*NOUT+o, then 128 root rows
    const unsigned int* __restrict__ entries,
    const int* __restrict__ cursor,
    const float* __restrict__ bias,
    unsigned short* __restrict__ H,         // layer-1 out (CLS=false)
    const float* __restrict__ Wc, const float* __restrict__ bc,
    float* __restrict__ out) {              // final logits (CLS=true)
  __shared__ __align__(16) unsigned char smem[CLS ? 34816 : 32768];
  unsigned short* Ms = reinterpret_cast<unsigned short*>(smem);
  const int tid = threadIdx.x;
  const int lane = tid & 63;
  const int wave = tid >> 6;
  const int d0 = blockIdx.x * 128;
  constexpr int JW = NOUT / 32;            // B-frags per wave: 4 (128-out) / 2 (64-out)
  const int wm = (wave >> 1) << 6;         // dst-half: 0/64
  const int wn = (wave & 1) * (NOUT / 2);  // out-col half
  const int l15 = lane & 15;
  const int quad = lane >> 4;
  const int g = quad;                      // edge group (gather phase)
  const int l16 = l15;                     // 16B feat chunk (gather phase)

  f32x4 acc[4][JW] = {};

  for (int r = 0; r < 8; ++r) {
    // ---- build m_r: each wave owns 32 dsts ----
    for (int t = 0; t < 32; ++t) {
      const int dl = (wave << 5) + t;
      const int d = d0 + dl;
      int deg = (d < NN) ? cursor[d * CSTRIDE] : 0;
      if (deg > CAP) deg = CAP;
      unsigned int e = (lane < deg) ? entries[(size_t)d * CAP + lane] : 0u;
      const bool match = (lane < deg) && (((e >> 16) & 7u) == (unsigned)r);
      unsigned long long bm = __ballot(match);
      int cnt = __popcll(bm);
      float sc = match ? __builtin_amdgcn_rcpf((float)cnt) : 0.f;
      float a[8] = {};
      const int T = (deg + 15) >> 4;
      for (int tt = 0; tt < T; ++tt) {
#pragma unroll
        for (int q = 0; q < 4; ++q) {
          const int slot = tt * 16 + q * 4 + g;     // uniform within 16-lane group
          unsigned int eq = __shfl(e, slot, 64);
          float sq = __shfl(sc, slot, 64);
          if (sq != 0.f) {                          // skip non-matching (keeps gathers 1x total)
            uint4 p = *reinterpret_cast<const uint4*>(
                X + (((size_t)(eq & 0xffffu)) << 7) + (l16 << 3));
            a[0] += b2f((unsigned short)p.x) * sq;
            a[1] += __uint_as_float(p.x & 0xffff0000u) * sq;
            a[2] += b2f((unsigned short)p.y) * sq;
            a[3] += __uint_as_float(p.y & 0xffff0000u) * sq;
            a[4] += b2f((unsigned short)p.z) * sq;
            a[5] += __uint_as_float(p.z & 0xffff0000u) * sq;
            a[6] += b2f((unsigned short)p.w) * sq;
            a[7] += __uint_as_float(p.w & 0xffff0000u) * sq;
          }
        }
      }
#pragma unroll
      for (int j2 = 0; j2 < 8; ++j2) {
        a[j2] += __shfl_xor(a[j2], 16, 64);
        a[j2] += __shfl_xor(a[j2], 32, 64);
      }
      if (g == 0) {   // write row dl of m_r (bf16, swizzled); zeros when deg==0
        uint4 o4;
        o4.x = (unsigned int)f2b(a[0]) | ((unsigned int)f2b(a[1]) << 16);
        o4.y = (unsigned int)f2b(a[2]) | ((unsigned int)f2b(a[3]) << 16);
        o4.z = (unsigned int)f2b(a[4]) | ((unsigned int)f2b(a[5]) << 16);
        o4.w = (unsigned int)f2b(a[6]) | ((unsigned int)f2b(a[7]) << 16);
        *reinterpret_cast<uint4*>(&Ms[dl * 128 + ((l16 ^ (dl & 15)) << 3)]) = o4;
      }
    }
    __syncthreads();
    // ---- MFMA: acc += m_r @ W_r (B-frags straight from L2-hot BT) ----
#pragma unroll
    for (int kk = 0; kk < 4; ++kk) {
      const int sw = ((kk * 4 + quad) ^ l15) << 3;
      bf16x8 af[4], bfr[JW];
#pragma unroll
      for (int i = 0; i < 4; ++i)
        af[i] = *reinterpret_cast<const bf16x8*>(&Ms[(wm + i * 16 + l15) * 128 + sw]);
#pragma unroll
      for (int j = 0; j < JW; ++j)
        bfr[j] = *reinterpret_cast<const bf16x8*>(
            BT + (size_t)(r * NOUT + wn + j * 16 + l15) * 128 + (kk * 4 + quad) * 8);
#pragma unroll
      for (int i = 0; i < 4; ++i)
#pragma unroll
        for (int j = 0; j < JW; ++j)
          acc[i][j] = __builtin_amdgcn_mfma_f32_16x16x32_bf16(bfr[j], af[i], acc[i][j], 0, 0, 0);
    }
    __syncthreads();   // m_r reads done before next pass overwrites
  }

  // ---- root pass: A = X rows d0.. (contiguous, no gather), B rows 8*NOUT.. ----
#pragma unroll
  for (int kk = 0; kk < 4; ++kk) {
    bf16x8 af[4], bfr[JW];
#pragma unroll
    for (int i = 0; i < 4; ++i) {
      int rA = d0 + wm + i * 16 + l15;
      if (rA > NN - 1) rA = NN - 1;   // ghost rows: clamped reads, stores guarded
      af[i] = *reinterpret_cast<const bf16x8*>(X + (size_t)rA * 128 + (kk * 4 + quad) * 8);
    }
#pragma unroll
    for (int j = 0; j < JW; ++j)
      bfr[j] = *reinterpret_cast<const bf16x8*>(
          BT + (size_t)(8 * NOUT + wn + j * 16 + l15) * 128 + (kk * 4 + quad) * 8);
#pragma unroll
    for (int i = 0; i < 4; ++i)
#pragma unroll
      for (int j = 0; j < JW; ++j)
        acc[i][j] = __builtin_amdgcn_mfma_f32_16x16x32_bf16(bfr[j], af[i], acc[i][j], 0, 0, 0);
  }

  if constexpr (!CLS) {
    // ---- bias + ReLU + shfl-transpose store H [N][128] bf16 ----
    const int tr = lane >> 2;
    const int tc = lane & 3;
    const int sl0 = ((tc & 1) << 1) * 16 + tr;
    const int sl1 = sl0 + 16;
    const bool thi = (tc & 2) != 0;
#pragma unroll
    for (int grp = 0; grp < 2; ++grp) {     // j-pairs (0,1),(2,3) -> 32-col halves
#pragma unroll
      for (int i = 0; i < 4; ++i) {
        float4 b0 = *reinterpret_cast<const float4*>(&bias[wn + grp * 32 + quad * 4]);
        float4 b1_ = *reinterpret_cast<const float4*>(&bias[wn + grp * 32 + 16 + quad * 4]);
        f32x4 v0 = acc[i][grp * 2 + 0], v1 = acc[i][grp * 2 + 1];
        float e0 = fmaxf(v0[0] + b0.x, 0.f), e1 = fmaxf(v0[1] + b0.y, 0.f);
        float e2 = fmaxf(v0[2] + b0.z, 0.f), e3 = fmaxf(v0[3] + b0.w, 0.f);
        float f0 = fmaxf(v1[0] + b1_.x, 0.f), f1 = fmaxf(v1[1] + b1_.y, 0.f);
        float f2 = fmaxf(v1[2] + b1_.z, 0.f), f3 = fmaxf(v1[3] + b1_.w, 0.f);
        uint2 pk0, pk1;
        pk0.x = (unsigned int)f2b(e0) | ((unsigned int)f2b(e1) << 16);
        pk0.y = (unsigned int)f2b(e2) | ((unsigned int)f2b(e3) << 16);
        pk1.x = (unsigned int)f2b(f0) | ((unsigned int)f2b(f1) << 16);
        pk1.y = (unsigned int)f2b(f2) | ((unsigned int)f2b(f3) << 16);
        unsigned int a0x = __shfl(pk0.x, sl0, 64), a0y = __shfl(pk0.y, sl0, 64);
        unsigned int a1x = __shfl(pk1.x, sl0, 64), a1y = __shfl(pk1.y, sl0, 64);
        unsigned int b0x = __shfl(pk0.x, sl1, 64), b0y = __shfl(pk0.y, sl1, 64);
        unsigned int b1x = __shfl(pk1.x, sl1, 64), b1y = __shfl(pk1.y, sl1, 64);
        uint4 o;
        o.x = thi ? a1x : a0x;
        o.y = thi ? a1y : a0y;
        o.z = thi ? b1x : b0x;
        o.w = thi ? b1y : b0y;
        const int m = wm + i * 16 + tr;
        if (d0 + m < NN)
          *reinterpret_cast<uint4*>(&H[(size_t)(d0 + m) * 128 + wn + grp * 32 + tc * 8]) = o;
      }
    }
  } else {
    // ---- bias + ReLU -> LDS f32 [128][68] (16B-aligned rows, 4-bank skew) ----
    float* hs = reinterpret_cast<float*>(smem);   // safe: Ms last read before final barrier
#pragma unroll
    for (int i = 0; i < 4; ++i) {
      const int row = wm + i * 16 + l15;
#pragma unroll
      for (int j = 0; j < JW; ++j) {
        const int col = wn + j * 16 + quad * 4;
        float4 b4 = *reinterpret_cast<const float4*>(&bias[col]);
        float4 v = make_float4(fmaxf(acc[i][j][0] + b4.x, 0.f),
                               fmaxf(acc[i][j][1] + b4.y, 0.f),
                               fmaxf(acc[i][j][2] + b4.z, 0.f),
                               fmaxf(acc[i][j][3] + b4.w, 0.f));
        *reinterpret_cast<float4*>(&hs[row * 68 + col]) = v;
      }
    }
    __syncthreads();
    // ---- fused classifier: thread dl < 128 -> out[d][2] ----
    if (tid < 128) {
      const int dl = tid;
      float p0 = 0.f, p1 = 0.f;
      for (int o = 0; o < 64; ++o) {
        float h = hs[dl * 68 + o];
        p0 += h * Wc[o * 2 + 0];
        p1 += h * Wc[o * 2 + 1];
      }
      const int d = d0 + dl;
      if (d < NN) {
        out[d * 2 + 0] = p0 + bc[0];
        out[d * 2 + 1] = p1 + bc[1];
      }
    }
  }
}

extern "C" void kernel_launch(void* const* d_in, const int* in_sizes, int n_in,
                              void* d_out, int out_size, void* d_ws, size_t ws_size,
                              hipStream_t stream) {
  const float* x     = (const float*)d_in[0];
  const int*   ei    = (const int*)d_in[1];
  const int*   et    = (const int*)d_in[2];
  const float* W1    = (const float*)d_in[3];
  const float* root1 = (const float*)d_in[4];
  const float* b1    = (const float*)d_in[5];
  const float* W2    = (const float*)d_in[6];
  const float* root2 = (const float*)d_in[7];
  const float* b2    = (const float*)d_in[8];
  const float* Wc    = (const float*)d_in[9];
  const float* bc    = (const float*)d_in[10];
  const int* srcI = ei;        // edge_index[0]
  const int* dstI = ei + EE;   // edge_index[1]

  char* ws = (char*)d_ws;
  unsigned short* xb      = (unsigned short*)(ws);             // 12,800,000 B
  unsigned short* B1T     = (unsigned short*)(ws + 12800000);  //    294,912 B
  unsigned short* B2T     = (unsigned short*)(ws + 13094912);  //    163,840 B
  int*            cursor  = (int*)(ws + 13258752);             //  3,200,000 B (64B-padded)
  unsigned int*   entries = (unsigned int*)(ws + 16458752);    //  9,600,000 B (50000*48*4)
  unsigned short* h1      = (unsigned short*)(ws + 26058752);  // 12,800,000 B
  // total: 38,858,752 B — no y1/y2/hpre buffers anymore

  hipMemsetAsync(cursor, 0, 3200000, stream);

  // prologue: conv + B1^T + B2^T + edge-list build
  const int PRO_N = CONV_N + B1_N + B2_N + EE;
  k_prologue<<<(PRO_N + 255) / 256, 256, 0, stream>>>(x, xb, W1, root1, B1T,
                                                      W2, root2, B2T,
                                                      srcI, dstI, et, cursor, entries);

  // fused layer 1: h1 = relu(sum_r mean_r(xb)@W1_r + xb@root1 + b1), bf16 [N][128]
  k_fused<128, false><<<391, 256, 0, stream>>>(xb, B1T, entries, cursor, b1,
                                               h1, nullptr, nullptr, nullptr);

  // fused layer 2 + classifier: out = relu(sum_r mean_r(h1)@W2_r + h1@root2 + b2) @ Wc + bc
  k_fused<64, true><<<391, 256, 0, stream>>>(h1, B2T, entries, cursor, b2,
                                             nullptr, Wc, bc, (float*)d_out);
}